// Round 4
// baseline (355.647 us; speedup 1.0000x reference)
//
#include <hip/hip_runtime.h>
#include <stdint.h>

typedef _Float16 f16;
typedef __attribute__((ext_vector_type(8))) _Float16 f16x8;
typedef __attribute__((ext_vector_type(4))) float f32x4;

// (1/sqrt(512)) * log2(e) folded into Q at projection time
#define QSCALE 0.0637587159f

__device__ __forceinline__ void gload16(const void* g, void* l) {
  __builtin_amdgcn_global_load_lds(
      (const __attribute__((address_space(1))) unsigned int*)(uintptr_t)g,
      (__attribute__((address_space(3))) unsigned int*)(uintptr_t)l,
      16, 0, 0);
}

// ---------------- prepass ----------------
__global__ __launch_bounds__(256) void k_cvt_x(const float* __restrict__ x,
                                               f16* __restrict__ xb) {
  const int i = (blockIdx.x * 256 + threadIdx.x) * 8;
  const float4 a = *(const float4*)(x + i);
  const float4 b = *(const float4*)(x + i + 4);
  f16x8 o;
  o[0] = (f16)a.x; o[1] = (f16)a.y; o[2] = (f16)a.z; o[3] = (f16)a.w;
  o[4] = (f16)b.x; o[5] = (f16)b.y; o[6] = (f16)b.z; o[7] = (f16)b.w;
  *(f16x8*)(xb + i) = o;
}

// Wq,Wk -> Wqkt[e'][d] (e'<512: Wq col e', else Wk col e'-512); Wv -> Wvt[e][d]
__global__ __launch_bounds__(256) void k_tw(const float* __restrict__ Wq,
                                            const float* __restrict__ Wk,
                                            const float* __restrict__ Wv,
                                            f16* __restrict__ Wqkt,
                                            f16* __restrict__ Wvt) {
  const int t = blockIdx.x * 256 + threadIdx.x;   // 768*256 = 196608
  const int mat = t >> 16;
  const int rem = t & 65535;
  const int e = rem & 511;
  const int d4 = (rem >> 9) << 2;
  const float* W = (mat == 0) ? Wq : (mat == 1 ? Wk : Wv);
  f16* dst = (mat == 0) ? (Wqkt + e * 512)
           : (mat == 1 ? (Wqkt + (512 + e) * 512) : (Wvt + e * 512));
#pragma unroll
  for (int i = 0; i < 4; i++) dst[d4 + i] = (f16)W[(d4 + i) * 512 + e];
}

// ---------------- shared 128x128x512 GEMM core ----------------
// C-tile = A[128 rows][512] * Bt[128 cols][512]^T, both row-major in K.
__device__ __forceinline__ void gemm_tile(const f16* __restrict__ Ag,
                                          const f16* __restrict__ Btg,
                                          f32x4 acc[4][4]) {
  __shared__ __align__(16) f16 As[128 * 64];
  __shared__ __align__(16) f16 Bs[128 * 64];
  const int lane = threadIdx.x & 63;
  const int w = threadIdx.x >> 6;
  const int wr = (w >> 1) * 64;
  const int wc = (w & 1) * 64;
#pragma unroll
  for (int i = 0; i < 4; i++)
#pragma unroll
    for (int j = 0; j < 4; j++) acc[i][j] = (f32x4){0.f, 0.f, 0.f, 0.f};

  for (int kt = 0; kt < 8; ++kt) {
    // stage: rows of A and Bt, 128B/row, swizzle via pre-swizzled global src
#pragma unroll
    for (int i = 0; i < 4; i++) {
      const int r = w * 32 + i * 8 + (lane >> 3);
      const int src = kt * 64 + (((lane & 7) * 8) ^ ((r & 7) << 3));
      gload16(Ag + r * 512 + src, &As[(w * 32 + i * 8) * 64]);
      gload16(Btg + r * 512 + src, &Bs[(w * 32 + i * 8) * 64]);
    }
    __syncthreads();
#pragma unroll
    for (int ks = 0; ks < 2; ++ks) {
      f16x8 a[4], bfr[4];
#pragma unroll
      for (int i = 0; i < 4; i++) {
        const int row = wr + i * 16 + (lane & 15);
        a[i] = *(const f16x8*)&As[row * 64 +
                 ((ks * 32 + 8 * (lane >> 4)) ^ ((row & 7) << 3))];
      }
#pragma unroll
      for (int j = 0; j < 4; j++) {
        const int row = wc + j * 16 + (lane & 15);
        bfr[j] = *(const f16x8*)&Bs[row * 64 +
                 ((ks * 32 + 8 * (lane >> 4)) ^ ((row & 7) << 3))];
      }
#pragma unroll
      for (int i = 0; i < 4; i++)
#pragma unroll
        for (int j = 0; j < 4; j++)
          acc[i][j] = __builtin_amdgcn_mfma_f32_16x16x32_f16(a[i], bfr[j],
                                                             acc[i][j], 0, 0, 0);
    }
    __syncthreads();
  }
}

// ---------------- Q|K projection ----------------
__global__ __launch_bounds__(256) void k_qk_proj(
    const f16* __restrict__ xb, const f16* __restrict__ Wqkt,
    const float* __restrict__ bq, const float* __restrict__ bk,
    f16* __restrict__ Q, f16* __restrict__ K) {
  const int rt = blockIdx.x, ct = blockIdx.y;
  f32x4 acc[4][4];
  gemm_tile(xb + rt * 128 * 512, Wqkt + ct * 128 * 512, acc);
  const int lane = threadIdx.x & 63;
  const int w = threadIdx.x >> 6;
  const int wr = (w >> 1) * 64, wc = (w & 1) * 64;
  const bool isQ = (ct < 4);
  const float* bias = isQ ? bq : bk;
  f16* dst = isQ ? Q : K;
  const int cb = (ct & 3) * 128;
  const float qs = isQ ? QSCALE : 1.0f;
#pragma unroll
  for (int j = 0; j < 4; j++) {
    const int col = cb + wc + j * 16 + (lane & 15);
    const float bb = bias[col];
#pragma unroll
    for (int i = 0; i < 4; i++) {
      const int nbase = rt * 128 + wr + i * 16 + 4 * (lane >> 4);
#pragma unroll
      for (int r = 0; r < 4; r++) {
        float v = fmaxf(acc[i][j][r] + bb, 0.f) * qs;
        dst[(nbase + r) * 512 + col] = (f16)v;
      }
    }
  }
}

// ---------------- V projection (stores V^T per batch) ----------------
__global__ __launch_bounds__(256) void k_v_proj(
    const f16* __restrict__ Wvt, const f16* __restrict__ xb,
    const float* __restrict__ bv, f16* __restrict__ Vt) {
  const int rt = blockIdx.x;  // e tile (0..3)
  const int ct = blockIdx.y;  // token tile (0..127)
  f32x4 acc[4][4];
  gemm_tile(Wvt + rt * 128 * 512, xb + ct * 128 * 512, acc);
  const int lane = threadIdx.x & 63;
  const int w = threadIdx.x >> 6;
  const int wr = (w >> 1) * 64, wc = (w & 1) * 64;
#pragma unroll
  for (int i = 0; i < 4; i++) {
    const int ebase = rt * 128 + wr + i * 16 + 4 * (lane >> 4);
#pragma unroll
    for (int j = 0; j < 4; j++) {
      const int n = ct * 128 + wc + j * 16 + (lane & 15);
      const int b = n >> 11, nb = n & 2047;
#pragma unroll
      for (int r = 0; r < 4; r++) {
        const int e = ebase + r;
        float v = fmaxf(acc[i][j][r] + bv[e], 0.f);
        Vt[(b * 512 + e) * 2048 + nb] = (f16)v;
      }
    }
  }
}

// ---------------- flash attention ----------------
__global__ __launch_bounds__(256) void k_attn(
    const f16* __restrict__ Q, const f16* __restrict__ K,
    const f16* __restrict__ Vt, float* __restrict__ out) {
  __shared__ __align__(16) f16 Ks[64 * 512];   // K tile, rows=k, swizzled
  __shared__ __align__(16) f16 Vs[512 * 64];   // V^T tile, rows=d, swizzled
  __shared__ __align__(16) f16 Ps[4][16 * 72]; // per-wave P, padded rows
  const int b = blockIdx.x & 7;                // batch -> XCD pin
  const int qb = blockIdx.x >> 3;
  const int lane = threadIdx.x & 63;
  const int w = threadIdx.x >> 6;
  const f16* Qg = Q + (b * 2048 + qb * 64) * 512;
  const f16* Kg = K + b * 2048 * 512;
  const f16* Vg = Vt + b * 512 * 2048;

  // stage Q (into Ks area), load register-resident Q fragments
#pragma unroll
  for (int i = 0; i < 16; i++) {
    const int r = w * 16 + i;
    const int src = (lane * 8) ^ ((r & 7) << 3);
    gload16(Qg + r * 512 + src, &Ks[r * 512]);
  }
  __syncthreads();
  f16x8 qf[16];
  {
    const int row = w * 16 + (lane & 15);
#pragma unroll
    for (int ks = 0; ks < 16; ++ks)
      qf[ks] = *(const f16x8*)&Ks[row * 512 +
               ((ks * 32 + 8 * (lane >> 4)) ^ ((row & 7) << 3))];
  }
  __syncthreads();

  f32x4 o[32];
#pragma unroll
  for (int i = 0; i < 32; i++) o[i] = (f32x4){0.f, 0.f, 0.f, 0.f};
  float m[4] = {-1e30f, -1e30f, -1e30f, -1e30f};
  float l[4] = {0.f, 0.f, 0.f, 0.f};

  for (int kt = 0; kt < 32; ++kt) {
    // stage K tile (64 rows x 1KB) and V^T tile (512 rows x 128B)
#pragma unroll
    for (int i = 0; i < 16; i++) {
      const int r = w * 16 + i;
      const int src = (lane * 8) ^ ((r & 7) << 3);
      gload16(Kg + (kt * 64 + r) * 512 + src, &Ks[r * 512]);
    }
#pragma unroll
    for (int i = 0; i < 16; i++) {
      const int r = w * 128 + i * 8 + (lane >> 3);
      const int src = kt * 64 + (((lane & 7) * 8) ^ ((r & 7) << 3));
      gload16(Vg + r * 2048 + src, &Vs[(w * 128 + i * 8) * 64]);
    }
    __syncthreads();

    // S = Q' K^T  (Q pre-scaled by log2e/sqrt(512))
    f32x4 s[4];
#pragma unroll
    for (int c = 0; c < 4; c++) s[c] = (f32x4){0.f, 0.f, 0.f, 0.f};
#pragma unroll
    for (int ks = 0; ks < 16; ++ks) {
#pragma unroll
      for (int c = 0; c < 4; c++) {
        const int row = c * 16 + (lane & 15);
        const f16x8 kf = *(const f16x8*)&Ks[row * 512 +
                        ((ks * 32 + 8 * (lane >> 4)) ^ ((row & 7) << 3))];
        s[c] = __builtin_amdgcn_mfma_f32_16x16x32_f16(qf[ks], kf, s[c], 0, 0, 0);
      }
    }

    // online softmax; rows live across the 16-lane (lane&15) group
    float sc[4];
#pragma unroll
    for (int r = 0; r < 4; r++) {
      float v = fmaxf(fmaxf(s[0][r], s[1][r]), fmaxf(s[2][r], s[3][r]));
      v = fmaxf(v, __shfl_xor(v, 1));
      v = fmaxf(v, __shfl_xor(v, 2));
      v = fmaxf(v, __shfl_xor(v, 4));
      v = fmaxf(v, __shfl_xor(v, 8));
      const float nm = fmaxf(m[r], v);
      sc[r] = exp2f(m[r] - nm);
      m[r] = nm;
      float rs = 0.f;
      const int prow = 4 * (lane >> 4) + r;
#pragma unroll
      for (int c = 0; c < 4; c++) {
        const float pv = exp2f(s[c][r] - nm);
        Ps[w][prow * 72 + c * 16 + (lane & 15)] = (f16)pv;
        rs += pv;
      }
      rs += __shfl_xor(rs, 1);
      rs += __shfl_xor(rs, 2);
      rs += __shfl_xor(rs, 4);
      rs += __shfl_xor(rs, 8);
      l[r] = l[r] * sc[r] + rs;
    }
    {
      const f32x4 scv = {sc[0], sc[1], sc[2], sc[3]};
#pragma unroll
      for (int i = 0; i < 32; i++) o[i] *= scv;
    }

    // O += P V  (P via LDS to get A-fragment layout)
    const f16x8 pf0 = *(const f16x8*)&Ps[w][(lane & 15) * 72 + 8 * (lane >> 4)];
    const f16x8 pf1 = *(const f16x8*)&Ps[w][(lane & 15) * 72 + 32 + 8 * (lane >> 4)];
#pragma unroll
    for (int dt = 0; dt < 32; ++dt) {
      const int row = dt * 16 + (lane & 15);
      const f16x8 v0 = *(const f16x8*)&Vs[row * 64 +
                      ((8 * (lane >> 4)) ^ ((row & 7) << 3))];
      const f16x8 v1 = *(const f16x8*)&Vs[row * 64 +
                      ((32 + 8 * (lane >> 4)) ^ ((row & 7) << 3))];
      o[dt] = __builtin_amdgcn_mfma_f32_16x16x32_f16(pf0, v0, o[dt], 0, 0, 0);
      o[dt] = __builtin_amdgcn_mfma_f32_16x16x32_f16(pf1, v1, o[dt], 0, 0, 0);
    }
    __syncthreads();
  }

  float rl[4];
#pragma unroll
  for (int r = 0; r < 4; r++) rl[r] = 1.0f / l[r];
  float* ob = out + ((b * 2048 + qb * 64 + w * 16 + 4 * (lane >> 4)) * 512) + (lane & 15);
#pragma unroll
  for (int dt = 0; dt < 32; ++dt)
#pragma unroll
    for (int r = 0; r < 4; r++)
      ob[r * 512 + dt * 16] = o[dt][r] * rl[r];
}

// ---------------- launch ----------------
extern "C" void kernel_launch(void* const* d_in, const int* in_sizes, int n_in,
                              void* d_out, int out_size, void* d_ws, size_t ws_size,
                              hipStream_t stream) {
  const float* x  = (const float*)d_in[0];
  const float* Wq = (const float*)d_in[1];
  const float* bq = (const float*)d_in[2];
  const float* Wk = (const float*)d_in[3];
  const float* bk = (const float*)d_in[4];
  const float* Wv = (const float*)d_in[5];
  const float* bv = (const float*)d_in[6];
  float* out = (float*)d_out;
  char* ws = (char*)d_ws;

  f16* xb   = (f16*)(ws);                                   // 16 MB
  f16* Wqkt = (f16*)(ws + 16777216);                        // 1 MB
  f16* Wvt  = (f16*)(ws + 16777216 + 1048576);              // 0.5 MB
  f16* Qb   = (f16*)(ws + 18350080);                        // 16 MB
  f16* Kb   = (f16*)(ws + 18350080 + 16777216);             // 16 MB
  f16* Vtb  = (f16*)(ws + 18350080 + 2 * 16777216);         // 16 MB  (total ~69 MB)

  // x: B*N*D = 8*2048*512 = 8,388,608 floats; 8 elts/thread -> 4096 blocks
  hipLaunchKernelGGL(k_cvt_x, dim3(4096), dim3(256), 0, stream, x, xb);
  hipLaunchKernelGGL(k_tw, dim3(768), dim3(256), 0, stream, Wq, Wk, Wv, Wqkt, Wvt);
  hipLaunchKernelGGL(k_qk_proj, dim3(128, 8), dim3(256), 0, stream, xb, Wqkt, bq, bk, Qb, Kb);
  hipLaunchKernelGGL(k_v_proj, dim3(4, 128), dim3(256), 0, stream, Wvt, xb, bv, Vtb);
  hipLaunchKernelGGL(k_attn, dim3(256), dim3(256), 0, stream, Qb, Kb, Vtb, out);
}

// Round 7
// 328.424 us; speedup vs baseline: 1.0829x; 1.0829x over previous
//
#include <hip/hip_runtime.h>
#include <stdint.h>

typedef _Float16 f16;
typedef __attribute__((ext_vector_type(8))) _Float16 f16x8;
typedef __attribute__((ext_vector_type(4))) float f32x4;

// (1/sqrt(512)) * log2(e) folded into Q at projection time
#define QSCALE 0.0637587159f

__device__ __forceinline__ void gload16(const void* g, void* l) {
  __builtin_amdgcn_global_load_lds(
      (const __attribute__((address_space(1))) unsigned int*)(uintptr_t)g,
      (__attribute__((address_space(3))) unsigned int*)(uintptr_t)l,
      16, 0, 0);
}

// ---------------- prepass ----------------
__global__ __launch_bounds__(256) void k_cvt_x(const float* __restrict__ x,
                                               f16* __restrict__ xb) {
  const int i = (blockIdx.x * 256 + threadIdx.x) * 8;
  const float4 a = *(const float4*)(x + i);
  const float4 b = *(const float4*)(x + i + 4);
  f16x8 o;
  o[0] = (f16)a.x; o[1] = (f16)a.y; o[2] = (f16)a.z; o[3] = (f16)a.w;
  o[4] = (f16)b.x; o[5] = (f16)b.y; o[6] = (f16)b.z; o[7] = (f16)b.w;
  *(f16x8*)(xb + i) = o;
}

// Wq,Wk -> Wqkt[e'][d] (e'<512: Wq col e', else Wk col e'-512); Wv -> Wvt[e][d]
__global__ __launch_bounds__(256) void k_tw(const float* __restrict__ Wq,
                                            const float* __restrict__ Wk,
                                            const float* __restrict__ Wv,
                                            f16* __restrict__ Wqkt,
                                            f16* __restrict__ Wvt) {
  const int t = blockIdx.x * 256 + threadIdx.x;   // 768*256 = 196608
  const int mat = t >> 16;
  const int rem = t & 65535;
  const int e = rem & 511;
  const int d4 = (rem >> 9) << 2;
  const float* W = (mat == 0) ? Wq : (mat == 1 ? Wk : Wv);
  f16* dst = (mat == 0) ? (Wqkt + e * 512)
           : (mat == 1 ? (Wqkt + (512 + e) * 512) : (Wvt + e * 512));
#pragma unroll
  for (int i = 0; i < 4; i++) dst[d4 + i] = (f16)W[(d4 + i) * 512 + e];
}

// ---------------- shared 128x128x512 GEMM core ----------------
// C-tile = A[128 rows][512] * Bt[128 cols][512]^T, both row-major in K.
__device__ __forceinline__ void gemm_tile(const f16* __restrict__ Ag,
                                          const f16* __restrict__ Btg,
                                          f32x4 acc[4][4]) {
  __shared__ __align__(16) f16 As[128 * 64];
  __shared__ __align__(16) f16 Bs[128 * 64];
  const int lane = threadIdx.x & 63;
  const int w = threadIdx.x >> 6;
  const int wr = (w >> 1) * 64;
  const int wc = (w & 1) * 64;
#pragma unroll
  for (int i = 0; i < 4; i++)
#pragma unroll
    for (int j = 0; j < 4; j++) acc[i][j] = (f32x4){0.f, 0.f, 0.f, 0.f};

  for (int kt = 0; kt < 8; ++kt) {
    // stage: rows of A and Bt, 128B/row, swizzle via pre-swizzled global src
#pragma unroll
    for (int i = 0; i < 4; i++) {
      const int r = w * 32 + i * 8 + (lane >> 3);
      const int src = kt * 64 + (((lane & 7) * 8) ^ ((r & 7) << 3));
      gload16(Ag + r * 512 + src, &As[(w * 32 + i * 8) * 64]);
      gload16(Btg + r * 512 + src, &Bs[(w * 32 + i * 8) * 64]);
    }
    __syncthreads();
#pragma unroll
    for (int ks = 0; ks < 2; ++ks) {
      f16x8 a[4], bfr[4];
#pragma unroll
      for (int i = 0; i < 4; i++) {
        const int row = wr + i * 16 + (lane & 15);
        a[i] = *(const f16x8*)&As[row * 64 +
                 ((ks * 32 + 8 * (lane >> 4)) ^ ((row & 7) << 3))];
      }
#pragma unroll
      for (int j = 0; j < 4; j++) {
        const int row = wc + j * 16 + (lane & 15);
        bfr[j] = *(const f16x8*)&Bs[row * 64 +
                 ((ks * 32 + 8 * (lane >> 4)) ^ ((row & 7) << 3))];
      }
#pragma unroll
      for (int i = 0; i < 4; i++)
#pragma unroll
        for (int j = 0; j < 4; j++)
          acc[i][j] = __builtin_amdgcn_mfma_f32_16x16x32_f16(a[i], bfr[j],
                                                             acc[i][j], 0, 0, 0);
    }
    __syncthreads();
  }
}

// ---------------- Q|K projection ----------------
__global__ __launch_bounds__(256) void k_qk_proj(
    const f16* __restrict__ xb, const f16* __restrict__ Wqkt,
    const float* __restrict__ bq, const float* __restrict__ bk,
    f16* __restrict__ Q, f16* __restrict__ K) {
  const int rt = blockIdx.x, ct = blockIdx.y;
  f32x4 acc[4][4];
  gemm_tile(xb + rt * 128 * 512, Wqkt + ct * 128 * 512, acc);
  const int lane = threadIdx.x & 63;
  const int w = threadIdx.x >> 6;
  const int wr = (w >> 1) * 64, wc = (w & 1) * 64;
  const bool isQ = (ct < 4);
  const float* bias = isQ ? bq : bk;
  f16* dst = isQ ? Q : K;
  const int cb = (ct & 3) * 128;
  const float qs = isQ ? QSCALE : 1.0f;
#pragma unroll
  for (int j = 0; j < 4; j++) {
    const int col = cb + wc + j * 16 + (lane & 15);
    const float bb = bias[col];
#pragma unroll
    for (int i = 0; i < 4; i++) {
      const int nbase = rt * 128 + wr + i * 16 + 4 * (lane >> 4);
#pragma unroll
      for (int r = 0; r < 4; r++) {
        float v = fmaxf(acc[i][j][r] + bb, 0.f) * qs;
        dst[(nbase + r) * 512 + col] = (f16)v;
      }
    }
  }
}

// ---------------- V projection (stores V^T per batch) ----------------
__global__ __launch_bounds__(256) void k_v_proj(
    const f16* __restrict__ Wvt, const f16* __restrict__ xb,
    const float* __restrict__ bv, f16* __restrict__ Vt) {
  const int rt = blockIdx.x;  // e tile (0..3)
  const int ct = blockIdx.y;  // token tile (0..127)
  f32x4 acc[4][4];
  gemm_tile(Wvt + rt * 128 * 512, xb + ct * 128 * 512, acc);
  const int lane = threadIdx.x & 63;
  const int w = threadIdx.x >> 6;
  const int wr = (w >> 1) * 64, wc = (w & 1) * 64;
#pragma unroll
  for (int i = 0; i < 4; i++) {
    const int ebase = rt * 128 + wr + i * 16 + 4 * (lane >> 4);
#pragma unroll
    for (int j = 0; j < 4; j++) {
      const int n = ct * 128 + wc + j * 16 + (lane & 15);
      const int b = n >> 11, nb = n & 2047;
#pragma unroll
      for (int r = 0; r < 4; r++) {
        const int e = ebase + r;
        float v = fmaxf(acc[i][j][r] + bv[e], 0.f);
        Vt[(b * 512 + e) * 2048 + nb] = (f16)v;
      }
    }
  }
}

// ---------------- flash attention (double-buffered KVBLK=32) ----------------
__global__ __launch_bounds__(256) void k_attn(
    const f16* __restrict__ Q, const f16* __restrict__ K,
    const f16* __restrict__ Vt, float* __restrict__ out) {
  // unified LDS: Kbuf0 | Kbuf1 | Vbuf0 | Vbuf1 | Ps   (140,288 B)
  // K buf c at smem + c*16384 ([32][512]); V buf c at smem + 32768 + c*16384
  // ([512][32]); Ps at smem + 65536 ([4][16*72]).
  __shared__ __align__(16) f16 smem[70144];
  const int b = blockIdx.x & 7;                     // batch -> XCD pin
  const int qb = blockIdx.x >> 3;
  const int lane = threadIdx.x & 63;
  const int w = threadIdx.x >> 6;
  const f16* Qg = Q + (b * 2048 + qb * 64) * 512;
  const f16* Kg = K + b * 2048 * 512;
  const f16* Vg = Vt + b * 512 * 2048;
  f16* const Ps = smem + 65536;

  // stage Q (64 rows x 1KB) into the K-buffer region, pull fragments to regs
#pragma unroll
  for (int i = 0; i < 16; i++) {
    const int r = w * 16 + i;
    const int src = (lane * 8) ^ ((r & 7) << 3);
    gload16(Qg + r * 512 + src, &smem[r * 512]);
  }
  __syncthreads();
  f16x8 qf[16];
  {
    const int row = w * 16 + (lane & 15);
#pragma unroll
    for (int ks = 0; ks < 16; ++ks)
      qf[ks] = *(const f16x8*)&smem[row * 512 +
               ((ks * 32 + 8 * (lane >> 4)) ^ ((row & 7) << 3))];
  }
  __syncthreads();

  // prologue: stage tile 0 into buffer 0
#pragma unroll
  for (int i = 0; i < 8; i++) {
    const int r = w * 8 + i;
    gload16(Kg + r * 512 + ((lane * 8) ^ ((r & 7) << 3)), smem + r * 512);
  }
#pragma unroll
  for (int i = 0; i < 8; i++) {
    const int row = w * 128 + i * 16 + (lane >> 2);
    const int col = (8 * (lane & 3)) ^ (8 * ((row >> 1) & 3));
    gload16(Vg + row * 2048 + col, smem + 32768 + (w * 128 + i * 16) * 32);
  }
  __syncthreads();

  f32x4 o[32];
#pragma unroll
  for (int i = 0; i < 32; i++) o[i] = (f32x4){0.f, 0.f, 0.f, 0.f};
  float m[4] = {-1e30f, -1e30f, -1e30f, -1e30f};
  float l[4] = {0.f, 0.f, 0.f, 0.f};
  int cur = 0;

  for (int kt = 0; kt < 64; ++kt) {
    // issue next tile's stage FIRST (into the other buffer); latency hides
    // under this iteration's compute; iter-end __syncthreads drains vmcnt.
    if (kt < 63) {
      const f16* Kgn = Kg + (kt + 1) * 32 * 512;
      const f16* Vgn = Vg + (kt + 1) * 32;
      f16* kd = smem + (cur ^ 1) * 16384;
      f16* vd = smem + 32768 + (cur ^ 1) * 16384;
#pragma unroll
      for (int i = 0; i < 8; i++) {
        const int r = w * 8 + i;
        gload16(Kgn + r * 512 + ((lane * 8) ^ ((r & 7) << 3)), kd + r * 512);
      }
#pragma unroll
      for (int i = 0; i < 8; i++) {
        const int row = w * 128 + i * 16 + (lane >> 2);
        const int col = (8 * (lane & 3)) ^ (8 * ((row >> 1) & 3));
        gload16(Vgn + row * 2048 + col, vd + (w * 128 + i * 16) * 32);
      }
    }
    const f16* Ks = smem + cur * 16384;
    const f16* Vs = smem + 32768 + cur * 16384;

    // S = Q' K^T  (Q pre-scaled by log2e/sqrt(512)); S is 16q x 32k per wave
    f32x4 s[2];
#pragma unroll
    for (int c = 0; c < 2; c++) s[c] = (f32x4){0.f, 0.f, 0.f, 0.f};
#pragma unroll
    for (int ks = 0; ks < 16; ++ks) {
#pragma unroll
      for (int c = 0; c < 2; c++) {
        const int row = c * 16 + (lane & 15);
        const f16x8 kf = *(const f16x8*)&Ks[row * 512 +
                        ((ks * 32 + 8 * (lane >> 4)) ^ ((row & 7) << 3))];
        s[c] = __builtin_amdgcn_mfma_f32_16x16x32_f16(qf[ks], kf, s[c], 0, 0, 0);
      }
    }

    // online softmax; rows live across the 16-lane (lane&15) group
    float sc[4];
#pragma unroll
    for (int r = 0; r < 4; r++) {
      float v = fmaxf(s[0][r], s[1][r]);
      v = fmaxf(v, __shfl_xor(v, 1));
      v = fmaxf(v, __shfl_xor(v, 2));
      v = fmaxf(v, __shfl_xor(v, 4));
      v = fmaxf(v, __shfl_xor(v, 8));
      const float nm = fmaxf(m[r], v);
      sc[r] = exp2f(m[r] - nm);
      m[r] = nm;
      float rs = 0.f;
      const int prow = 4 * (lane >> 4) + r;
#pragma unroll
      for (int c = 0; c < 2; c++) {
        const float pv = exp2f(s[c][r] - nm);
        Ps[w * 1152 + prow * 72 + c * 16 + (lane & 15)] = (f16)pv;
        rs += pv;
      }
      rs += __shfl_xor(rs, 1);
      rs += __shfl_xor(rs, 2);
      rs += __shfl_xor(rs, 4);
      rs += __shfl_xor(rs, 8);
      l[r] = l[r] * sc[r] + rs;
    }
    {
      const f32x4 scv = {sc[0], sc[1], sc[2], sc[3]};
#pragma unroll
      for (int i = 0; i < 32; i++) o[i] *= scv;
    }

    // O += P V  (P via LDS to get A-fragment layout; K=32 -> single pf)
    const f16x8 pf = *(const f16x8*)&Ps[w * 1152 + (lane & 15) * 72 +
                                        8 * (lane >> 4)];
#pragma unroll
    for (int dt = 0; dt < 32; ++dt) {
      const int row = dt * 16 + (lane & 15);
      const f16x8 v0 = *(const f16x8*)&Vs[row * 32 +
                      ((8 * (lane >> 4)) ^ (8 * ((row >> 1) & 3)))];
      o[dt] = __builtin_amdgcn_mfma_f32_16x16x32_f16(pf, v0, o[dt], 0, 0, 0);
    }
    __syncthreads();   // drains stage vmcnt + barrier: next buffer ready
    cur ^= 1;
  }

  float rl[4];
#pragma unroll
  for (int r = 0; r < 4; r++) rl[r] = 1.0f / l[r];
  float* ob = out + ((b * 2048 + qb * 64 + w * 16 + 4 * (lane >> 4)) * 512) + (lane & 15);
#pragma unroll
  for (int dt = 0; dt < 32; ++dt)
#pragma unroll
    for (int r = 0; r < 4; r++)
      ob[r * 512 + dt * 16] = o[dt][r] * rl[r];
}

// ---------------- launch ----------------
extern "C" void kernel_launch(void* const* d_in, const int* in_sizes, int n_in,
                              void* d_out, int out_size, void* d_ws, size_t ws_size,
                              hipStream_t stream) {
  const float* x  = (const float*)d_in[0];
  const float* Wq = (const float*)d_in[1];
  const float* bq = (const float*)d_in[2];
  const float* Wk = (const float*)d_in[3];
  const float* bk = (const float*)d_in[4];
  const float* Wv = (const float*)d_in[5];
  const float* bv = (const float*)d_in[6];
  float* out = (float*)d_out;
  char* ws = (char*)d_ws;

  f16* xb   = (f16*)(ws);                                   // 16 MB
  f16* Wqkt = (f16*)(ws + 16777216);                        // 1 MB
  f16* Wvt  = (f16*)(ws + 16777216 + 1048576);              // 0.5 MB
  f16* Qb   = (f16*)(ws + 18350080);                        // 16 MB
  f16* Kb   = (f16*)(ws + 18350080 + 16777216);             // 16 MB
  f16* Vtb  = (f16*)(ws + 18350080 + 2 * 16777216);         // 16 MB  (total ~69 MB)

  // x: B*N*D = 8*2048*512 = 8,388,608 floats; 8 elts/thread -> 4096 blocks
  hipLaunchKernelGGL(k_cvt_x, dim3(4096), dim3(256), 0, stream, x, xb);
  hipLaunchKernelGGL(k_tw, dim3(768), dim3(256), 0, stream, Wq, Wk, Wv, Wqkt, Wvt);
  hipLaunchKernelGGL(k_qk_proj, dim3(128, 8), dim3(256), 0, stream, xb, Wqkt, bq, bk, Qb, Kb);
  hipLaunchKernelGGL(k_v_proj, dim3(4, 128), dim3(256), 0, stream, Wvt, xb, bv, Vtb);
  hipLaunchKernelGGL(k_attn, dim3(256), dim3(256), 0, stream, Qb, Kb, Vtb, out);
}